// Round 4
// baseline (658.004 us; speedup 1.0000x reference)
//
#include <hip/hip_runtime.h>
#include <math.h>

#define BB 4
#define SS 2048
#define DD 512
#define NN 16
#define LL 4
#define VV 256
#define CC 64            // scan chunks
#define TT (SS / CC)     // 32 steps per chunk
#define EPSL 1e-5f
#define MM (BB * SS)     // 8192 rows
#define KI 16            // K-iterations = 512/32

typedef __bf16 bf16;
typedef __attribute__((ext_vector_type(8))) __bf16 bf16x8;
typedef __attribute__((ext_vector_type(4))) __bf16 bf16x4;
typedef __attribute__((ext_vector_type(4))) float f32x4;

// Packed fragment layout for a [rows][512] bf16 matrix:
//   tile = row>>4, fm = row&15, ki = k>>5, fq = (k>>3)&3, e = k&7
//   flat = tile*8192 + ki*512 + fq*128 + fm*8 + e
// => a wave's MFMA fragment load (16x16x32) is  base + (tile*16+ki)*512 + lane*8,
//    i.e. one contiguous 1KB global_load_dwordx4 per fragment.

// ---------------- embed: X[b,s,d] = emb_byte[ids[b,s],d] + emb_pos[s,d] ----
__global__ void embed_kernel(const int* __restrict__ ids,
                             const float* __restrict__ eb,
                             const float* __restrict__ ep,
                             float* __restrict__ X) {
    int idx = blockIdx.x * 256 + threadIdx.x;      // over B*S*D
    int d = idx % DD;
    int s = (idx / DD) % SS;
    int b = idx / (DD * SS);
    X[idx] = eb[(size_t)ids[b * SS + s] * DD + d] + ep[(size_t)s * DD + d];
}

// ---------------- weight convert: fp32 [K][N] -> packed bf16 fragments -----
// WtP layout: 4 layers x (64 n-tiles x 8192) [Wd cols 0-511, WDp cols 512-1023],
// then head 16 n-tiles x 8192. One thread per 16B output chunk (278528 chunks).
__global__ void convert_weights(const float* __restrict__ Wd,
                                const float* __restrict__ WDp,
                                const float* __restrict__ Wh,
                                bf16* __restrict__ WtP) {
    int c = blockIdx.x * 256 + threadIdx.x;
    if (c >= 278528) return;
    bf16x8 v;
    if (c < 262144) {                       // layer weights: 65536 chunks/layer
        int l = c >> 16;
        int cc = c & 65535;
        int tile = cc >> 10;                // 64 n-tiles
        int wc = cc & 1023;
        int ki = wc >> 6, fq = (wc >> 4) & 3, fm = wc & 15;
        int n = tile * 16 + fm;
        int k0 = ki * 32 + fq * 8;
        const float* s = (n < DD) ? (Wd + (size_t)l * DD * DD + n)
                                  : (WDp + (size_t)l * DD * DD + (n - DD));
#pragma unroll
        for (int e = 0; e < 8; e++) v[e] = (bf16)s[(size_t)(k0 + e) * DD];
    } else {                                // head: 16384 chunks
        int ch = c - 262144;
        int tile = ch >> 10;
        int wc = ch & 1023;
        int ki = wc >> 6, fq = (wc >> 4) & 3, fm = wc & 15;
        int n = tile * 16 + fm;
        int k0 = ki * 32 + fq * 8;
#pragma unroll
        for (int e = 0; e < 8; e++) v[e] = (bf16)Wh[(size_t)(k0 + e) * VV + n];
    }
    *(bf16x8*)(WtP + (size_t)c * 8) = v;
}

// ---------------- layernorm: writes fp32 HN + packed bf16 HNb --------------
__global__ void ln_kernel(const float* __restrict__ X,
                          const float* __restrict__ gamma,
                          const float* __restrict__ beta,
                          float* __restrict__ HN, bf16* __restrict__ HNb) {
    int wave = threadIdx.x >> 6;
    int lane = threadIdx.x & 63;
    int row = blockIdx.x * 4 + wave;
    const float* xr = X + (size_t)row * DD;
    float4 v0 = *(const float4*)(xr + lane * 4);
    float4 v1 = *(const float4*)(xr + 256 + lane * 4);
    float s = v0.x + v0.y + v0.z + v0.w + v1.x + v1.y + v1.z + v1.w;
    float q = v0.x * v0.x + v0.y * v0.y + v0.z * v0.z + v0.w * v0.w +
              v1.x * v1.x + v1.y * v1.y + v1.z * v1.z + v1.w * v1.w;
#pragma unroll
    for (int o = 1; o < 64; o <<= 1) {
        s += __shfl_xor(s, o);
        q += __shfl_xor(q, o);
    }
    float m = s * (1.0f / DD);
    float var = q * (1.0f / DD) - m * m;
    float rs = rsqrtf(var + EPSL);
    float4 g0 = *(const float4*)(gamma + lane * 4);
    float4 g1 = *(const float4*)(gamma + 256 + lane * 4);
    float4 b0 = *(const float4*)(beta + lane * 4);
    float4 b1 = *(const float4*)(beta + 256 + lane * 4);
    float* hr = HN + (size_t)row * DD;
    float4 o0, o1;
    o0.x = (v0.x - m) * rs * g0.x + b0.x;
    o0.y = (v0.y - m) * rs * g0.y + b0.y;
    o0.z = (v0.z - m) * rs * g0.z + b0.z;
    o0.w = (v0.w - m) * rs * g0.w + b0.w;
    o1.x = (v1.x - m) * rs * g1.x + b1.x;
    o1.y = (v1.y - m) * rs * g1.y + b1.y;
    o1.z = (v1.z - m) * rs * g1.z + b1.z;
    o1.w = (v1.w - m) * rs * g1.w + b1.w;
    *(float4*)(hr + lane * 4) = o0;
    *(float4*)(hr + 256 + lane * 4) = o1;
    // packed bf16 write: lane covers k = lane*4..+3 (ki=lane>>3) and +256 (ki+8)
    int tile = row >> 4, fm = row & 15;
    size_t pb = (size_t)tile * 8192 + (size_t)(lane >> 3) * 512 +
                (size_t)((lane & 7) >> 1) * 128 + fm * 8 + (lane & 1) * 4;
    bf16x4 p0 = {(bf16)o0.x, (bf16)o0.y, (bf16)o0.z, (bf16)o0.w};
    bf16x4 p1 = {(bf16)o1.x, (bf16)o1.y, (bf16)o1.z, (bf16)o1.w};
    *(bf16x4*)(HNb + pb) = p0;
    *(bf16x4*)(HNb + pb + 8 * 512) = p1;
}

// ---------------- barrier-free MFMA GEMM from packed fragments -------------
// Block = 4 waves (2x2), 128x128 tile, warp-tile 64x64. Register double-buffer,
// no LDS, no __syncthreads. XCD swizzle: 8 m-tiles per XCD, all n-tiles local.
// MODE 0 (head): O1[row*Nout+col] = acc + bias[col]
// MODE 1 (layer, Nout=1024): col<512 -> DEL=softplus; col>=512 -> D2=+bias2+Xres
template <int MODE>
__global__ __launch_bounds__(256, 2) void gemm_pack(const bf16* __restrict__ Ap,
                                                    const bf16* __restrict__ Bp,
                                                    const float* __restrict__ bias,
                                                    const float* __restrict__ bias2,
                                                    const float* __restrict__ Xres,
                                                    float* __restrict__ O1,
                                                    float* __restrict__ O2, int Nout) {
    const int tid = threadIdx.x, wave = tid >> 6, lane = tid & 63;
    const int lin = blockIdx.x;
    const int xcd = lin & 7, i4 = lin >> 3;
    const int mt = xcd * 8 + (i4 & 7);      // m-tile (128 rows), 64 total
    const int nb = i4 >> 3;                 // n-tile (128 cols)
    const int mw = mt * 8 + (wave >> 1) * 4;  // warp m base in 16-row units
    const int nw = nb * 8 + (wave & 1) * 4;   // warp n base in 16-col units
    const bf16* Aw = Ap + (size_t)mw * 8192 + lane * 8;
    const bf16* Bw = Bp + (size_t)nw * 8192 + lane * 8;

    f32x4 acc[4][4];
#pragma unroll
    for (int i = 0; i < 4; i++)
#pragma unroll
        for (int j = 0; j < 4; j++) acc[i][j] = (f32x4){0.f, 0.f, 0.f, 0.f};

    bf16x8 a[2][4], b[2][4];
#pragma unroll
    for (int i = 0; i < 4; i++) {
        a[0][i] = *(const bf16x8*)(Aw + (size_t)i * 8192);
        b[0][i] = *(const bf16x8*)(Bw + (size_t)i * 8192);
    }
#pragma unroll
    for (int ki = 0; ki < KI; ki++) {
        const int cur = ki & 1, nxt = cur ^ 1;
        if (ki < KI - 1) {
#pragma unroll
            for (int i = 0; i < 4; i++) {
                a[nxt][i] = *(const bf16x8*)(Aw + (size_t)i * 8192 + (ki + 1) * 512);
                b[nxt][i] = *(const bf16x8*)(Bw + (size_t)i * 8192 + (ki + 1) * 512);
            }
        }
#pragma unroll
        for (int i = 0; i < 4; i++)
#pragma unroll
            for (int j = 0; j < 4; j++)
                acc[i][j] = __builtin_amdgcn_mfma_f32_16x16x32_bf16(a[cur][i], b[cur][j],
                                                                    acc[i][j], 0, 0, 0);
    }

    const int fm = lane & 15, fq = lane >> 4;
#pragma unroll
    for (int i = 0; i < 4; i++) {
#pragma unroll
        for (int j = 0; j < 4; j++) {
            int col = (nw + j) * 16 + fm;
#pragma unroll
            for (int r = 0; r < 4; r++) {
                int row = (mw + i) * 16 + fq * 4 + r;
                float v = acc[i][j][r];
                if (MODE == 0) {
                    O1[(size_t)row * Nout + col] = v + bias[col];
                } else {
                    if (col < DD) {
                        v += bias[col];
                        v = fmaxf(v, 0.0f) + log1pf(__expf(-fabsf(v)));
                        O1[(size_t)row * DD + col] = v;
                    } else {
                        int c = col - DD;
                        O2[(size_t)row * DD + c] = v + bias2[c] + Xres[(size_t)row * DD + c];
                    }
                }
            }
        }
    }
}

// ---------------- fused small GEMMs: BI/CI[M,16] = HN @ {WB,WC} + bias -----
__global__ void gemmBC(const float* __restrict__ HN,
                       const float* __restrict__ WB, const float* __restrict__ bB,
                       const float* __restrict__ WC, const float* __restrict__ bC,
                       float* __restrict__ BI, float* __restrict__ CI) {
    int tid = threadIdx.x;
    int col = tid & 15;
    int row = blockIdx.x * 16 + (tid >> 4);
    const float* ar = HN + (size_t)row * DD;
    float accB = 0.0f, accC = 0.0f;
#pragma unroll 8
    for (int k = 0; k < DD; k++) {
        float a = ar[k];
        accB = fmaf(a, WB[k * NN + col], accB);
        accC = fmaf(a, WC[k * NN + col], accC);
    }
    BI[(size_t)row * NN + col] = accB + bB[col];
    CI[(size_t)row * NN + col] = accC + bC[col];
}

// ---------------- scan phase 1: per-(b,d,chunk) local scan from zero -------
__global__ __launch_bounds__(512) void scan1(const float* __restrict__ DEL,
                                             const float* __restrict__ HNp,
                                             const float* __restrict__ BI,
                                             const float* __restrict__ logA,
                                             float* __restrict__ P,
                                             float* __restrict__ LSt) {
    int b = blockIdx.x / CC, c = blockIdx.x % CC;
    int d = threadIdx.x;
    float Ar[NN], prod[NN], st[NN];
#pragma unroll
    for (int n = 0; n < NN; n++) {
        Ar[n] = -__expf(logA[d * NN + n]);
        prod[n] = 1.0f;
        st[n] = 0.0f;
    }
    int t0 = c * TT;
    for (int t = t0; t < t0 + TT; t++) {
        size_t base = (size_t)b * SS + t;
        float dl = DEL[base * DD + d];
        float du = dl * HNp[base * DD + d];
        const float* bi = BI + base * NN;
#pragma unroll
        for (int n = 0; n < NN; n++) {
            float a = __expf(dl * Ar[n]);
            prod[n] *= a;
            st[n] = fmaf(a, st[n], du * bi[n]);
        }
    }
    size_t o = (((size_t)b * DD + d) * CC + c) * NN;
#pragma unroll
    for (int n = 0; n < NN; n++) {
        P[o + n] = prod[n];
        LSt[o + n] = st[n];
    }
}

// ---------------- scan phase 2: sequential combine; LS becomes init state --
__global__ void scan2(const float* __restrict__ P, float* __restrict__ LS) {
    int tid = blockIdx.x * 256 + threadIdx.x;  // over B*D*N = 32768
    int n = tid & (NN - 1);
    int d = (tid / NN) & (DD - 1);
    int b = tid / (NN * DD);
    size_t base = ((size_t)b * DD + d) * CC;
    float s = 0.0f;
    for (int c = 0; c < CC; c++) {
        size_t o = base * NN + (size_t)c * NN + n;
        float p = P[o];
        float ls = LS[o];
        LS[o] = s;                 // in-place: becomes chunk-initial state
        s = fmaf(p, s, ls);
    }
}

// ---------------- scan phase 3: re-scan with true init, emit X + packed bf16
__global__ __launch_bounds__(512) void scan3(const float* __restrict__ DEL,
                                             const float* __restrict__ HNp,
                                             const float* __restrict__ BI,
                                             const float* __restrict__ CI,
                                             const float* __restrict__ logA,
                                             const float* __restrict__ SIN,
                                             const float* __restrict__ D2,
                                             float* __restrict__ X,
                                             bf16* __restrict__ XB) {
    int b = blockIdx.x / CC, c = blockIdx.x % CC;
    int d = threadIdx.x;
    float Ar[NN], st[NN];
    size_t o = (((size_t)b * DD + d) * CC + c) * NN;
#pragma unroll
    for (int n = 0; n < NN; n++) {
        Ar[n] = -__expf(logA[d * NN + n]);
        st[n] = SIN[o + n];
    }
    int ki = d >> 5, fq = (d >> 3) & 3, e = d & 7;
    int t0 = c * TT;
    for (int t = t0; t < t0 + TT; t++) {
        size_t base = (size_t)b * SS + t;
        float dl = DEL[base * DD + d];
        float du = dl * HNp[base * DD + d];
        const float* bi = BI + base * NN;
        const float* ci = CI + base * NN;
        float y = 0.0f;
#pragma unroll
        for (int n = 0; n < NN; n++) {
            float a = __expf(dl * Ar[n]);
            st[n] = fmaf(a, st[n], du * bi[n]);
            y = fmaf(st[n], ci[n], y);
        }
        float xv = D2[base * DD + d] + y;
        X[base * DD + d] = xv;
        // packed bf16 write for the head GEMM
        int tile = (int)(base >> 4), fm = (int)(base & 15);
        XB[(size_t)tile * 8192 + ki * 512 + fq * 128 + fm * 8 + e] = (bf16)xv;
    }
}

extern "C" void kernel_launch(void* const* d_in, const int* in_sizes, int n_in,
                              void* d_out, int out_size, void* d_ws, size_t ws_size,
                              hipStream_t stream) {
    const int* ids = (const int*)d_in[0];
    const float* eb = (const float*)d_in[1];
    const float* ep = (const float*)d_in[2];
    const float* logA = (const float*)d_in[3];
    const float* Wd = (const float*)d_in[4];
    const float* bd = (const float*)d_in[5];
    const float* WB = (const float*)d_in[6];
    const float* bB = (const float*)d_in[7];
    const float* WC = (const float*)d_in[8];
    const float* bC = (const float*)d_in[9];
    const float* WDp = (const float*)d_in[10];
    const float* bDp = (const float*)d_in[11];
    const float* gamma = (const float*)d_in[12];
    const float* beta = (const float*)d_in[13];
    const float* Wh = (const float*)d_in[14];
    const float* bh = (const float*)d_in[15];
    float* out = (float*)d_out;

    size_t E = (size_t)MM * DD;                // 4,194,304 floats
    size_t EN = (size_t)MM * NN;               // 131,072
    size_t EC = (size_t)BB * DD * CC * NN;     // 2,097,152
    float* X = (float*)d_ws;
    float* HN = X + E;
    float* DEL = HN + E;
    float* D2 = DEL + E;
    float* BIc = D2 + E;
    float* CIc = BIc + EN;
    float* P = CIc + EN;
    float* LS = P + EC;
    bf16* HNb = (bf16*)(LS + EC);              // packed, E bf16 = 8 MB
    bf16* WtP = HNb + E;                       // packed weights: 278528*8 bf16

    embed_kernel<<<(MM * DD) / 256, 256, 0, stream>>>(ids, eb, ep, X);
    convert_weights<<<1088, 256, 0, stream>>>(Wd, WDp, Wh, WtP);
    for (int l = 0; l < LL; l++) {
        const float* lA = logA + (size_t)l * DD * NN;
        ln_kernel<<<MM / 4, 256, 0, stream>>>(X, gamma + l * DD, beta + l * DD, HN, HNb);
        gemm_pack<1><<<512, 256, 0, stream>>>(
            HNb, WtP + (size_t)l * 524288, bd + l * DD, bDp + l * DD, X, DEL, D2, 1024);
        gemmBC<<<MM / 16, 256, 0, stream>>>(HN, WB + (size_t)l * DD * NN, bB + l * NN,
                                            WC + (size_t)l * DD * NN, bC + l * NN, BIc, CIc);
        scan1<<<BB * CC, 512, 0, stream>>>(DEL, HN, BIc, lA, P, LS);
        scan2<<<(BB * DD * NN) / 256, 256, 0, stream>>>(P, LS);
        scan3<<<BB * CC, 512, 0, stream>>>(DEL, HN, BIc, CIc, lA, LS, D2, X, HNb);
    }
    // head: reads packed bf16(X_final) written by last scan3
    gemm_pack<0><<<128, 256, 0, stream>>>(
        HNb, WtP + (size_t)2097152, bh, nullptr, nullptr, out, nullptr, VV);
}

// Round 6
// 575.797 us; speedup vs baseline: 1.1428x; 1.1428x over previous
//
#include <hip/hip_runtime.h>
#include <math.h>

#define BB 4
#define SS 2048
#define DD 512
#define NN 16
#define LL 4
#define VV 256
#define CC 64            // scan chunks
#define TT (SS / CC)     // 32 steps per chunk
#define EPSL 1e-5f
#define MM (BB * SS)     // 8192 rows
#define KI 16            // K-iterations = 512/32

typedef __bf16 bf16;
typedef __attribute__((ext_vector_type(8))) __bf16 bf16x8;
typedef __attribute__((ext_vector_type(4))) __bf16 bf16x4;
typedef __attribute__((ext_vector_type(4))) float f32x4;

// Packed fragment layout for a [rows][512] bf16 matrix:
//   tile = row>>4, fm = row&15, ki = k>>5, fq = (k>>3)&3, e = k&7
//   flat = tile*8192 + ki*512 + fq*128 + fm*8 + e
// => one MFMA fragment = 1KB contiguous; global_load_lds stages it with
//    per-lane global addr base + lane*16B (its native addressing) and
//    ds_read_b128 at lane*16B is stride-1 (2 lanes/bank = conflict-free).

#define GLD_LDS(g, l) \
    __builtin_amdgcn_global_load_lds((__attribute__((address_space(1))) void*)(void*)(g), \
                                     (__attribute__((address_space(3))) void*)(l), 16, 0, 0)

// ---------------- embed: X[b,s,d] = emb_byte[ids[b,s],d] + emb_pos[s,d] ----
__global__ void embed_kernel(const int* __restrict__ ids,
                             const float* __restrict__ eb,
                             const float* __restrict__ ep,
                             float* __restrict__ X) {
    int idx = blockIdx.x * 256 + threadIdx.x;      // over B*S*D
    int d = idx % DD;
    int s = (idx / DD) % SS;
    int b = idx / (DD * SS);
    X[idx] = eb[(size_t)ids[b * SS + s] * DD + d] + ep[(size_t)s * DD + d];
}

// ---------------- weight convert: fp32 [K][N] -> packed bf16 fragments -----
__global__ void convert_weights(const float* __restrict__ Wd,
                                const float* __restrict__ WDp,
                                const float* __restrict__ Wh,
                                bf16* __restrict__ WtP) {
    int c = blockIdx.x * 256 + threadIdx.x;
    if (c >= 278528) return;
    bf16x8 v;
    if (c < 262144) {                       // layer weights: 65536 chunks/layer
        int l = c >> 16;
        int cc = c & 65535;
        int tile = cc >> 10;                // 64 n-tiles
        int wc = cc & 1023;
        int ki = wc >> 6, fq = (wc >> 4) & 3, fm = wc & 15;
        int n = tile * 16 + fm;
        int k0 = ki * 32 + fq * 8;
        const float* s = (n < DD) ? (Wd + (size_t)l * DD * DD + n)
                                  : (WDp + (size_t)l * DD * DD + (n - DD));
#pragma unroll
        for (int e = 0; e < 8; e++) v[e] = (bf16)s[(size_t)(k0 + e) * DD];
    } else {                                // head: 16384 chunks
        int ch = c - 262144;
        int tile = ch >> 10;
        int wc = ch & 1023;
        int ki = wc >> 6, fq = (wc >> 4) & 3, fm = wc & 15;
        int n = tile * 16 + fm;
        int k0 = ki * 32 + fq * 8;
#pragma unroll
        for (int e = 0; e < 8; e++) v[e] = (bf16)Wh[(size_t)(k0 + e) * VV + n];
    }
    *(bf16x8*)(WtP + (size_t)c * 8) = v;
}

// ---------------- layernorm: writes fp32 HN + packed bf16 HNb --------------
__global__ void ln_kernel(const float* __restrict__ X,
                          const float* __restrict__ gamma,
                          const float* __restrict__ beta,
                          float* __restrict__ HN, bf16* __restrict__ HNb) {
    int wave = threadIdx.x >> 6;
    int lane = threadIdx.x & 63;
    int row = blockIdx.x * 4 + wave;
    const float* xr = X + (size_t)row * DD;
    float4 v0 = *(const float4*)(xr + lane * 4);
    float4 v1 = *(const float4*)(xr + 256 + lane * 4);
    float s = v0.x + v0.y + v0.z + v0.w + v1.x + v1.y + v1.z + v1.w;
    float q = v0.x * v0.x + v0.y * v0.y + v0.z * v0.z + v0.w * v0.w +
              v1.x * v1.x + v1.y * v1.y + v1.z * v1.z + v1.w * v1.w;
#pragma unroll
    for (int o = 1; o < 64; o <<= 1) {
        s += __shfl_xor(s, o);
        q += __shfl_xor(q, o);
    }
    float m = s * (1.0f / DD);
    float var = q * (1.0f / DD) - m * m;
    float rs = rsqrtf(var + EPSL);
    float4 g0 = *(const float4*)(gamma + lane * 4);
    float4 g1 = *(const float4*)(gamma + 256 + lane * 4);
    float4 b0 = *(const float4*)(beta + lane * 4);
    float4 b1 = *(const float4*)(beta + 256 + lane * 4);
    float* hr = HN + (size_t)row * DD;
    float4 o0, o1;
    o0.x = (v0.x - m) * rs * g0.x + b0.x;
    o0.y = (v0.y - m) * rs * g0.y + b0.y;
    o0.z = (v0.z - m) * rs * g0.z + b0.z;
    o0.w = (v0.w - m) * rs * g0.w + b0.w;
    o1.x = (v1.x - m) * rs * g1.x + b1.x;
    o1.y = (v1.y - m) * rs * g1.y + b1.y;
    o1.z = (v1.z - m) * rs * g1.z + b1.z;
    o1.w = (v1.w - m) * rs * g1.w + b1.w;
    *(float4*)(hr + lane * 4) = o0;
    *(float4*)(hr + 256 + lane * 4) = o1;
    // packed bf16 write
    int tile = row >> 4, fm = row & 15;
    size_t pb = (size_t)tile * 8192 + (size_t)(lane >> 3) * 512 +
                (size_t)((lane & 7) >> 1) * 128 + fm * 8 + (lane & 1) * 4;
    bf16x4 p0 = {(bf16)o0.x, (bf16)o0.y, (bf16)o0.z, (bf16)o0.w};
    bf16x4 p1 = {(bf16)o1.x, (bf16)o1.y, (bf16)o1.z, (bf16)o1.w};
    *(bf16x4*)(HNb + pb) = p0;
    *(bf16x4*)(HNb + pb + 8 * 512) = p1;
}

// ---------------- MFMA GEMM: 64x64 tile, packed frags, LDS-staged ----------
// 4 waves in 2x2; each wave = 32x32 (2x2 fragments). 8 blocks/CU target.
// XCD swizzle: each XCD owns 16 m-strips x all n-tiles (A+B L2-resident).
// MODE 0 (head, NT=4): O1 = acc + bias
// MODE 1 (layer, NT=16): col<512 -> DEL=softplus; col>=512 -> D2=+bias2+Xres
template <int MODE, int NT>
__global__ __launch_bounds__(256, 8) void gemm_pack(const bf16* __restrict__ Ap,
                                                    const bf16* __restrict__ Bp,
                                                    const float* __restrict__ bias,
                                                    const float* __restrict__ bias2,
                                                    const float* __restrict__ Xres,
                                                    float* __restrict__ O1,
                                                    float* __restrict__ O2, int Nout) {
    __shared__ bf16 As[4 * 512];   // 4 KB
    __shared__ bf16 Bs[4 * 512];   // 4 KB
    const int tid = threadIdx.x, wave = tid >> 6, lane = tid & 63;
    const int lin = blockIdx.x;
    const int xcd = lin & 7, i4 = lin >> 3;
    const int ms = xcd * 16 + (i4 & 15);   // m-strip (64 rows), 128 total
    const int nb = i4 >> 4;                // n-tile (64 cols), NT total

    // staging: wave w stages A-frag (ms*4+w) and B-frag (nb*4+w)
    // NOTE: global address MUST be per-lane (+ lane*8 elems = lane*16 B);
    // LDS side is wave-uniform base + lane*16 implicitly (R5 bug was here).
    const bf16* gA = Ap + ((size_t)ms * 4 + wave) * 8192 + lane * 8;
    const bf16* gB = Bp + ((size_t)nb * 4 + wave) * 8192 + lane * 8;
    bf16* lA = As + wave * 512;
    bf16* lB = Bs + wave * 512;

    // wave 2x2 arrangement: A-half = wave>>1, B-half = wave&1
    const int fa0 = (wave >> 1) * 2, fb0 = (wave & 1) * 2;

    f32x4 acc[2][2];
#pragma unroll
    for (int i = 0; i < 2; i++)
#pragma unroll
        for (int j = 0; j < 2; j++) acc[i][j] = (f32x4){0.f, 0.f, 0.f, 0.f};

    for (int ki = 0; ki < KI; ki++) {
        GLD_LDS(gA + ki * 512, lA);
        GLD_LDS(gB + ki * 512, lB);
        __syncthreads();
        bf16x8 af[2], bfr[2];
#pragma unroll
        for (int i = 0; i < 2; i++) af[i] = *(const bf16x8*)(As + (fa0 + i) * 512 + lane * 8);
#pragma unroll
        for (int j = 0; j < 2; j++) bfr[j] = *(const bf16x8*)(Bs + (fb0 + j) * 512 + lane * 8);
#pragma unroll
        for (int i = 0; i < 2; i++)
#pragma unroll
            for (int j = 0; j < 2; j++)
                acc[i][j] = __builtin_amdgcn_mfma_f32_16x16x32_bf16(af[i], bfr[j], acc[i][j], 0, 0, 0);
        __syncthreads();
    }

    const int fm = lane & 15, fq = lane >> 4;
#pragma unroll
    for (int i = 0; i < 2; i++) {
#pragma unroll
        for (int j = 0; j < 2; j++) {
            int col = (nb * 4 + fb0 + j) * 16 + fm;
#pragma unroll
            for (int r = 0; r < 4; r++) {
                int row = (ms * 4 + fa0 + i) * 16 + fq * 4 + r;
                float v = acc[i][j][r];
                if (MODE == 0) {
                    O1[(size_t)row * Nout + col] = v + bias[col];
                } else {
                    if (col < DD) {
                        v += bias[col];
                        v = fmaxf(v, 0.0f) + log1pf(__expf(-fabsf(v)));
                        O1[(size_t)row * DD + col] = v;
                    } else {
                        int c = col - DD;
                        O2[(size_t)row * DD + c] = v + bias2[c] + Xres[(size_t)row * DD + c];
                    }
                }
            }
        }
    }
}

// ---------------- fused small GEMMs: BI/CI[M,16] = HN @ {WB,WC} + bias -----
__global__ void gemmBC(const float* __restrict__ HN,
                       const float* __restrict__ WB, const float* __restrict__ bB,
                       const float* __restrict__ WC, const float* __restrict__ bC,
                       float* __restrict__ BI, float* __restrict__ CI) {
    int tid = threadIdx.x;
    int col = tid & 15;
    int row = blockIdx.x * 16 + (tid >> 4);
    const float* ar = HN + (size_t)row * DD;
    float accB = 0.0f, accC = 0.0f;
#pragma unroll 8
    for (int k = 0; k < DD; k++) {
        float a = ar[k];
        accB = fmaf(a, WB[k * NN + col], accB);
        accC = fmaf(a, WC[k * NN + col], accC);
    }
    BI[(size_t)row * NN + col] = accB + bB[col];
    CI[(size_t)row * NN + col] = accC + bC[col];
}

// ---------------- scan phase 1: per-(b,d,chunk) local scan from zero -------
__global__ __launch_bounds__(512) void scan1(const float* __restrict__ DEL,
                                             const float* __restrict__ HNp,
                                             const float* __restrict__ BI,
                                             const float* __restrict__ logA,
                                             float* __restrict__ P,
                                             float* __restrict__ LSt) {
    int b = blockIdx.x / CC, c = blockIdx.x % CC;
    int d = threadIdx.x;
    float Ar[NN], prod[NN], st[NN];
#pragma unroll
    for (int n = 0; n < NN; n++) {
        Ar[n] = -__expf(logA[d * NN + n]);
        prod[n] = 1.0f;
        st[n] = 0.0f;
    }
    int t0 = c * TT;
    for (int t = t0; t < t0 + TT; t++) {
        size_t base = (size_t)b * SS + t;
        float dl = DEL[base * DD + d];
        float du = dl * HNp[base * DD + d];
        const float* bi = BI + base * NN;
#pragma unroll
        for (int n = 0; n < NN; n++) {
            float a = __expf(dl * Ar[n]);
            prod[n] *= a;
            st[n] = fmaf(a, st[n], du * bi[n]);
        }
    }
    size_t o = (((size_t)b * DD + d) * CC + c) * NN;
#pragma unroll
    for (int n = 0; n < NN; n++) {
        P[o + n] = prod[n];
        LSt[o + n] = st[n];
    }
}

// ---------------- scan phase 2: sequential combine; LS becomes init state --
__global__ void scan2(const float* __restrict__ P, float* __restrict__ LS) {
    int tid = blockIdx.x * 256 + threadIdx.x;  // over B*D*N = 32768
    int n = tid & (NN - 1);
    int d = (tid / NN) & (DD - 1);
    int b = tid / (NN * DD);
    size_t base = ((size_t)b * DD + d) * CC;
    float s = 0.0f;
    for (int c = 0; c < CC; c++) {
        size_t o = base * NN + (size_t)c * NN + n;
        float p = P[o];
        float ls = LS[o];
        LS[o] = s;                 // in-place: becomes chunk-initial state
        s = fmaf(p, s, ls);
    }
}

// ---------------- scan phase 3: re-scan with true init, emit X + packed bf16
__global__ __launch_bounds__(512) void scan3(const float* __restrict__ DEL,
                                             const float* __restrict__ HNp,
                                             const float* __restrict__ BI,
                                             const float* __restrict__ CI,
                                             const float* __restrict__ logA,
                                             const float* __restrict__ SIN,
                                             const float* __restrict__ D2,
                                             float* __restrict__ X,
                                             bf16* __restrict__ XB) {
    int b = blockIdx.x / CC, c = blockIdx.x % CC;
    int d = threadIdx.x;
    float Ar[NN], st[NN];
    size_t o = (((size_t)b * DD + d) * CC + c) * NN;
#pragma unroll
    for (int n = 0; n < NN; n++) {
        Ar[n] = -__expf(logA[d * NN + n]);
        st[n] = SIN[o + n];
    }
    int ki = d >> 5, fq = (d >> 3) & 3, e = d & 7;
    int t0 = c * TT;
    for (int t = t0; t < t0 + TT; t++) {
        size_t base = (size_t)b * SS + t;
        float dl = DEL[base * DD + d];
        float du = dl * HNp[base * DD + d];
        const float* bi = BI + base * NN;
        const float* ci = CI + base * NN;
        float y = 0.0f;
#pragma unroll
        for (int n = 0; n < NN; n++) {
            float a = __expf(dl * Ar[n]);
            st[n] = fmaf(a, st[n], du * bi[n]);
            y = fmaf(st[n], ci[n], y);
        }
        float xv = D2[base * DD + d] + y;
        X[base * DD + d] = xv;
        int tile = (int)(base >> 4), fm = (int)(base & 15);
        XB[(size_t)tile * 8192 + ki * 512 + fq * 128 + fm * 8 + e] = (bf16)xv;
    }
}

extern "C" void kernel_launch(void* const* d_in, const int* in_sizes, int n_in,
                              void* d_out, int out_size, void* d_ws, size_t ws_size,
                              hipStream_t stream) {
    const int* ids = (const int*)d_in[0];
    const float* eb = (const float*)d_in[1];
    const float* ep = (const float*)d_in[2];
    const float* logA = (const float*)d_in[3];
    const float* Wd = (const float*)d_in[4];
    const float* bd = (const float*)d_in[5];
    const float* WB = (const float*)d_in[6];
    const float* bB = (const float*)d_in[7];
    const float* WC = (const float*)d_in[8];
    const float* bC = (const float*)d_in[9];
    const float* WDp = (const float*)d_in[10];
    const float* bDp = (const float*)d_in[11];
    const float* gamma = (const float*)d_in[12];
    const float* beta = (const float*)d_in[13];
    const float* Wh = (const float*)d_in[14];
    const float* bh = (const float*)d_in[15];
    float* out = (float*)d_out;

    size_t E = (size_t)MM * DD;                // 4,194,304 floats
    size_t EN = (size_t)MM * NN;               // 131,072
    size_t EC = (size_t)BB * DD * CC * NN;     // 2,097,152
    float* X = (float*)d_ws;
    float* HN = X + E;
    float* DEL = HN + E;
    float* D2 = DEL + E;
    float* BIc = D2 + E;
    float* CIc = BIc + EN;
    float* P = CIc + EN;
    float* LS = P + EC;
    bf16* HNb = (bf16*)(LS + EC);              // packed, E bf16 = 8 MB
    bf16* WtP = HNb + E;                       // packed weights: 278528*8 bf16

    embed_kernel<<<(MM * DD) / 256, 256, 0, stream>>>(ids, eb, ep, X);
    convert_weights<<<1088, 256, 0, stream>>>(Wd, WDp, Wh, WtP);
    for (int l = 0; l < LL; l++) {
        const float* lA = logA + (size_t)l * DD * NN;
        ln_kernel<<<MM / 4, 256, 0, stream>>>(X, gamma + l * DD, beta + l * DD, HN, HNb);
        gemm_pack<1, 16><<<2048, 256, 0, stream>>>(
            HNb, WtP + (size_t)l * 524288, bd + l * DD, bDp + l * DD, X, DEL, D2, 1024);
        gemmBC<<<MM / 16, 256, 0, stream>>>(HN, WB + (size_t)l * DD * NN, bB + l * NN,
                                            WC + (size_t)l * DD * NN, bC + l * NN, BIc, CIc);
        scan1<<<BB * CC, 512, 0, stream>>>(DEL, HN, BIc, lA, P, LS);
        scan2<<<(BB * DD * NN) / 256, 256, 0, stream>>>(P, LS);
        scan3<<<BB * CC, 512, 0, stream>>>(DEL, HN, BIc, CIc, lA, LS, D2, X, HNb);
    }
    // head: reads packed bf16(X_final) written by last scan3
    gemm_pack<0, 4><<<512, 256, 0, stream>>>(
        HNb, WtP + (size_t)2097152, bh, nullptr, nullptr, out, nullptr, VV);
}

// Round 7
// 540.251 us; speedup vs baseline: 1.2180x; 1.0658x over previous
//
#include <hip/hip_runtime.h>
#include <math.h>

#define BB 4
#define SS 2048
#define DD 512
#define NN 16
#define LL 4
#define VV 256
#define CC 64            // scan chunks
#define TT (SS / CC)     // 32 steps per chunk
#define EPSL 1e-5f
#define MM (BB * SS)     // 8192 rows
#define KI 16            // K-iterations = 512/32
#define LPAD 528         // padded LDS row stride (floats): 16B-aligned, bank-shifted

typedef __bf16 bf16;
typedef __attribute__((ext_vector_type(8))) __bf16 bf16x8;
typedef __attribute__((ext_vector_type(4))) __bf16 bf16x4;
typedef __attribute__((ext_vector_type(4))) float f32x4;

// Packed fragment layout for a [rows][512] bf16 matrix:
//   tile = row>>4, fm = row&15, ki = k>>5, fq = (k>>3)&3, e = k&7
//   flat = tile*8192 + ki*512 + fq*128 + fm*8 + e
// => one MFMA fragment = 1KB contiguous; global_load_lds stages it with
//    per-lane global addr (base + lane*16B) and ds_read_b128 at lane*16B
//    is stride-1 (2 lanes/bank = conflict-free).

#define GLD_LDS(g, l) \
    __builtin_amdgcn_global_load_lds((__attribute__((address_space(1))) void*)(void*)(g), \
                                     (__attribute__((address_space(3))) void*)(l), 16, 0, 0)

// ---------------- shared LN row epilogue (wave holds one row of 512) -------
__device__ __forceinline__ void ln_row_write(float4 v0, float4 v1, int lane, size_t row,
                                             const float* __restrict__ gamma,
                                             const float* __restrict__ beta,
                                             float* HN, bf16* HNb) {
    float s = v0.x + v0.y + v0.z + v0.w + v1.x + v1.y + v1.z + v1.w;
    float q = v0.x * v0.x + v0.y * v0.y + v0.z * v0.z + v0.w * v0.w +
              v1.x * v1.x + v1.y * v1.y + v1.z * v1.z + v1.w * v1.w;
#pragma unroll
    for (int o = 1; o < 64; o <<= 1) {
        s += __shfl_xor(s, o);
        q += __shfl_xor(q, o);
    }
    float m = s * (1.0f / DD);
    float var = q * (1.0f / DD) - m * m;
    float rs = rsqrtf(var + EPSL);
    float4 g0 = *(const float4*)(gamma + lane * 4);
    float4 g1 = *(const float4*)(gamma + 256 + lane * 4);
    float4 b0 = *(const float4*)(beta + lane * 4);
    float4 b1 = *(const float4*)(beta + 256 + lane * 4);
    float4 o0, o1;
    o0.x = (v0.x - m) * rs * g0.x + b0.x;
    o0.y = (v0.y - m) * rs * g0.y + b0.y;
    o0.z = (v0.z - m) * rs * g0.z + b0.z;
    o0.w = (v0.w - m) * rs * g0.w + b0.w;
    o1.x = (v1.x - m) * rs * g1.x + b1.x;
    o1.y = (v1.y - m) * rs * g1.y + b1.y;
    o1.z = (v1.z - m) * rs * g1.z + b1.z;
    o1.w = (v1.w - m) * rs * g1.w + b1.w;
    float* hr = HN + row * DD;
    *(float4*)(hr + lane * 4) = o0;
    *(float4*)(hr + 256 + lane * 4) = o1;
    size_t pb = (size_t)(row >> 4) * 8192 + (size_t)(lane >> 3) * 512 +
                (size_t)((lane & 7) >> 1) * 128 + (row & 15) * 8 + (lane & 1) * 4;
    bf16x4 p0 = {(bf16)o0.x, (bf16)o0.y, (bf16)o0.z, (bf16)o0.w};
    bf16x4 p1 = {(bf16)o1.x, (bf16)o1.y, (bf16)o1.z, (bf16)o1.w};
    *(bf16x4*)(HNb + pb) = p0;
    *(bf16x4*)(HNb + pb + 8 * 512) = p1;
}

// ---------------- embed + layer-0 LN: X, HN, packed HNb in one pass --------
__global__ void embed_ln(const int* __restrict__ ids,
                         const float* __restrict__ eb,
                         const float* __restrict__ ep,
                         const float* __restrict__ gamma,
                         const float* __restrict__ beta,
                         float* __restrict__ X, float* HN, bf16* HNb) {
    int wave = threadIdx.x >> 6;
    int lane = threadIdx.x & 63;
    size_t row = blockIdx.x * 4 + wave;
    int s = (int)(row & (SS - 1));
    int id = ids[row];
    const float* ebr = eb + (size_t)id * DD;
    const float* epr = ep + (size_t)s * DD;
    float4 e0 = *(const float4*)(ebr + lane * 4);
    float4 e1 = *(const float4*)(ebr + 256 + lane * 4);
    float4 p0 = *(const float4*)(epr + lane * 4);
    float4 p1 = *(const float4*)(epr + 256 + lane * 4);
    float4 v0 = {e0.x + p0.x, e0.y + p0.y, e0.z + p0.z, e0.w + p0.w};
    float4 v1 = {e1.x + p1.x, e1.y + p1.y, e1.z + p1.z, e1.w + p1.w};
    *(float4*)(X + row * DD + lane * 4) = v0;
    *(float4*)(X + row * DD + 256 + lane * 4) = v1;
    ln_row_write(v0, v1, lane, row, gamma, beta, HN, HNb);
}

// ---------------- weight convert: coalesced LDS-slab transpose -> packed ---
// blk 0..255: layer n-tiles (l = blk>>6, tile = blk&63; tile<32 -> Wd, else WDp)
// blk 256..271: head n-tiles from Wh
__global__ __launch_bounds__(256) void convert_weights(const float* __restrict__ Wd,
                                                       const float* __restrict__ WDp,
                                                       const float* __restrict__ Wh,
                                                       bf16* __restrict__ WtP) {
    __shared__ float slab[512 * 17];
    int blk = blockIdx.x;
    const float* src;
    int nsrc, col0;
    bf16* dst;
    if (blk < 256) {
        int l = blk >> 6, tile = blk & 63;
        src = (tile < 32) ? (Wd + (size_t)l * DD * DD) : (WDp + (size_t)l * DD * DD);
        col0 = (tile & 31) * 16;
        nsrc = DD;
        dst = WtP + ((size_t)l * 64 + tile) * 8192;
    } else {
        int tile = blk - 256;
        src = Wh;
        col0 = tile * 16;
        nsrc = VV;
        dst = WtP + (size_t)(256 + tile) * 8192;
    }
    int tid = threadIdx.x;
    int kr = tid >> 2, cq = tid & 3;
#pragma unroll
    for (int i = 0; i < 8; i++) {
        int k = i * 64 + kr;
        float4 v = *(const float4*)(src + (size_t)k * nsrc + col0 + cq * 4);
        slab[k * 17 + cq * 4 + 0] = v.x;
        slab[k * 17 + cq * 4 + 1] = v.y;
        slab[k * 17 + cq * 4 + 2] = v.z;
        slab[k * 17 + cq * 4 + 3] = v.w;
    }
    __syncthreads();
#pragma unroll
    for (int it = 0; it < 4; it++) {
        int c = it * 256 + tid;
        int ki = c >> 6, fq = (c >> 4) & 3, fm = c & 15;
        int k0 = ki * 32 + fq * 8;
        bf16x8 v;
#pragma unroll
        for (int e = 0; e < 8; e++) v[e] = (bf16)slab[(k0 + e) * 17 + fm];
        *(bf16x8*)(dst + (size_t)c * 8) = v;
    }
}

// ---------------- MFMA GEMM: 64x64 tile, packed frags, LDS-staged ----------
// MODE 0 (head, NT=4): O1 = acc + bias
// MODE 1 (layer, NT=16): col<512 -> DEL=softplus; col>=512 -> D2=+bias2+Xres
template <int MODE, int NT>
__global__ __launch_bounds__(256, 8) void gemm_pack(const bf16* __restrict__ Ap,
                                                    const bf16* __restrict__ Bp,
                                                    const float* __restrict__ bias,
                                                    const float* __restrict__ bias2,
                                                    const float* __restrict__ Xres,
                                                    float* __restrict__ O1,
                                                    float* __restrict__ O2, int Nout) {
    __shared__ bf16 As[4 * 512];   // 4 KB
    __shared__ bf16 Bs[4 * 512];   // 4 KB
    const int tid = threadIdx.x, wave = tid >> 6, lane = tid & 63;
    const int lin = blockIdx.x;
    const int xcd = lin & 7, i4 = lin >> 3;
    const int ms = xcd * 16 + (i4 & 15);   // m-strip (64 rows), 128 total
    const int nb = i4 >> 4;                // n-tile (64 cols), NT total

    const bf16* gA = Ap + ((size_t)ms * 4 + wave) * 8192 + lane * 8;
    const bf16* gB = Bp + ((size_t)nb * 4 + wave) * 8192 + lane * 8;
    bf16* lA = As + wave * 512;
    bf16* lB = Bs + wave * 512;

    const int fa0 = (wave >> 1) * 2, fb0 = (wave & 1) * 2;

    f32x4 acc[2][2];
#pragma unroll
    for (int i = 0; i < 2; i++)
#pragma unroll
        for (int j = 0; j < 2; j++) acc[i][j] = (f32x4){0.f, 0.f, 0.f, 0.f};

    for (int ki = 0; ki < KI; ki++) {
        GLD_LDS(gA + ki * 512, lA);
        GLD_LDS(gB + ki * 512, lB);
        __syncthreads();
        bf16x8 af[2], bfr[2];
#pragma unroll
        for (int i = 0; i < 2; i++) af[i] = *(const bf16x8*)(As + (fa0 + i) * 512 + lane * 8);
#pragma unroll
        for (int j = 0; j < 2; j++) bfr[j] = *(const bf16x8*)(Bs + (fb0 + j) * 512 + lane * 8);
#pragma unroll
        for (int i = 0; i < 2; i++)
#pragma unroll
            for (int j = 0; j < 2; j++)
                acc[i][j] = __builtin_amdgcn_mfma_f32_16x16x32_bf16(af[i], bfr[j], acc[i][j], 0, 0, 0);
        __syncthreads();
    }

    const int fm = lane & 15, fq = lane >> 4;
#pragma unroll
    for (int i = 0; i < 2; i++) {
#pragma unroll
        for (int j = 0; j < 2; j++) {
            int col = (nb * 4 + fb0 + j) * 16 + fm;
#pragma unroll
            for (int r = 0; r < 4; r++) {
                int row = (ms * 4 + fa0 + i) * 16 + fq * 4 + r;
                float v = acc[i][j][r];
                if (MODE == 0) {
                    O1[(size_t)row * Nout + col] = v + bias[col];
                } else {
                    if (col < DD) {
                        v += bias[col];
                        v = fmaxf(v, 0.0f) + log1pf(__expf(-fabsf(v)));
                        O1[(size_t)row * DD + col] = v;
                    } else {
                        int c = col - DD;
                        O2[(size_t)row * DD + c] = v + bias2[c] + Xres[(size_t)row * DD + c];
                    }
                }
            }
        }
    }
}

// ---------------- scan1 + fused B/C projection ------------------------------
// Block (b,c): stage 32x512 HN chunk in LDS; compute BI/CI (fp32) for the
// chunk; then local scan from zero, emitting P and chunk-local states.
__global__ __launch_bounds__(512) void scan1bc(const float* __restrict__ DEL,
                                               const float* __restrict__ HN,
                                               const float* __restrict__ WB,
                                               const float* __restrict__ bB,
                                               const float* __restrict__ WC,
                                               const float* __restrict__ bC,
                                               const float* __restrict__ logA,
                                               float* __restrict__ P,
                                               float* __restrict__ LSt,
                                               float* __restrict__ BIo,
                                               float* __restrict__ CIo) {
    __shared__ float hn[32 * LPAD];     // 67.6 KB
    __shared__ float bis[32 * 16], cis[32 * 16];
    int b = blockIdx.x / CC, c = blockIdx.x % CC;
    size_t row0 = (size_t)b * SS + c * TT;
    const float* hsrc = HN + row0 * DD;
    for (int v = threadIdx.x; v < 4096; v += 512) {
        int t = v >> 7, qd = v & 127;
        float4 x = *(const float4*)(hsrc + (size_t)t * DD + qd * 4);
        *(float4*)(hn + t * LPAD + qd * 4) = x;
    }
    __syncthreads();
    {
        int t = threadIdx.x >> 4, col = threadIdx.x & 15;
        float aB = 0.0f, aC = 0.0f;
        const float* hr = hn + t * LPAD;
#pragma unroll 8
        for (int k = 0; k < DD; k++) {
            float h = hr[k];
            aB = fmaf(h, WB[k * NN + col], aB);
            aC = fmaf(h, WC[k * NN + col], aC);
        }
        aB += bB[col];
        aC += bC[col];
        bis[threadIdx.x] = aB;
        cis[threadIdx.x] = aC;
        BIo[row0 * NN + threadIdx.x] = aB;
        CIo[row0 * NN + threadIdx.x] = aC;
    }
    __syncthreads();
    int d = threadIdx.x;
    float Ar[NN], prod[NN], st[NN];
#pragma unroll
    for (int n = 0; n < NN; n++) {
        Ar[n] = -__expf(logA[d * NN + n]);
        prod[n] = 1.0f;
        st[n] = 0.0f;
    }
    for (int tt = 0; tt < TT; tt++) {
        size_t base = row0 + tt;
        float dl = DEL[base * DD + d];
        float du = dl * hn[tt * LPAD + d];
#pragma unroll
        for (int n = 0; n < NN; n++) {
            float a = __expf(dl * Ar[n]);
            prod[n] *= a;
            st[n] = fmaf(a, st[n], du * bis[tt * 16 + n]);
        }
    }
    size_t o = (((size_t)b * DD + d) * CC + c) * NN;
#pragma unroll
    for (int n = 0; n < NN; n++) {
        P[o + n] = prod[n];
        LSt[o + n] = st[n];
    }
}

// ---------------- scan phase 2: sequential combine; LS becomes init state --
__global__ void scan2(const float* __restrict__ P, float* __restrict__ LS) {
    int tid = blockIdx.x * 256 + threadIdx.x;  // over B*D*N = 32768
    int n = tid & (NN - 1);
    int d = (tid / NN) & (DD - 1);
    int b = tid / (NN * DD);
    size_t base = ((size_t)b * DD + d) * CC;
    float s = 0.0f;
    for (int c = 0; c < CC; c++) {
        size_t o = base * NN + (size_t)c * NN + n;
        float p = P[o];
        float ls = LS[o];
        LS[o] = s;                 // in-place: becomes chunk-initial state
        s = fmaf(p, s, ls);
    }
}

// ---------------- scan3 + fused next-layer LN -------------------------------
// Phase A: re-scan with true init, xv -> LDS (+X for !LAST).
// Phase B: wave-per-row LN -> HN (in-place) + packed HNb; LAST: packed raw.
template <int LAST>
__global__ __launch_bounds__(512) void scan3ln(const float* __restrict__ DEL,
                                               float* HN,
                                               const float* __restrict__ BI,
                                               const float* __restrict__ CI,
                                               const float* __restrict__ logA,
                                               const float* __restrict__ SIN,
                                               const float* __restrict__ D2,
                                               const float* __restrict__ gamma,
                                               const float* __restrict__ beta,
                                               float* __restrict__ X,
                                               bf16* HNb) {
    __shared__ float xvs[32 * LPAD];    // 67.6 KB
    int b = blockIdx.x / CC, c = blockIdx.x % CC;
    int d = threadIdx.x;
    float Ar[NN], st[NN];
    size_t o = (((size_t)b * DD + d) * CC + c) * NN;
#pragma unroll
    for (int n = 0; n < NN; n++) {
        Ar[n] = -__expf(logA[d * NN + n]);
        st[n] = SIN[o + n];
    }
    size_t row0 = (size_t)b * SS + c * TT;
    for (int tt = 0; tt < TT; tt++) {
        size_t base = row0 + tt;
        float dl = DEL[base * DD + d];
        float du = dl * HN[base * DD + d];
        const float* bi = BI + base * NN;
        const float* ci = CI + base * NN;
        float y = 0.0f;
#pragma unroll
        for (int n = 0; n < NN; n++) {
            float a = __expf(dl * Ar[n]);
            st[n] = fmaf(a, st[n], du * bi[n]);
            y = fmaf(st[n], ci[n], y);
        }
        float xv = D2[base * DD + d] + y;
        xvs[tt * LPAD + d] = xv;
        if (!LAST) X[base * DD + d] = xv;
    }
    __syncthreads();
    int wv = d >> 6, lane = d & 63;
#pragma unroll
    for (int r = 0; r < 4; r++) {
        int tt = wv * 4 + r;
        size_t row = row0 + tt;
        const float* xr = xvs + tt * LPAD;
        float4 v0 = *(const float4*)(xr + lane * 4);
        float4 v1 = *(const float4*)(xr + 256 + lane * 4);
        if (LAST) {
            size_t pb = (size_t)(row >> 4) * 8192 + (size_t)(lane >> 3) * 512 +
                        (size_t)((lane & 7) >> 1) * 128 + (row & 15) * 8 + (lane & 1) * 4;
            bf16x4 p0 = {(bf16)v0.x, (bf16)v0.y, (bf16)v0.z, (bf16)v0.w};
            bf16x4 p1 = {(bf16)v1.x, (bf16)v1.y, (bf16)v1.z, (bf16)v1.w};
            *(bf16x4*)(HNb + pb) = p0;
            *(bf16x4*)(HNb + pb + 8 * 512) = p1;
        } else {
            ln_row_write(v0, v1, lane, row, gamma, beta, HN, HNb);
        }
    }
}

extern "C" void kernel_launch(void* const* d_in, const int* in_sizes, int n_in,
                              void* d_out, int out_size, void* d_ws, size_t ws_size,
                              hipStream_t stream) {
    const int* ids = (const int*)d_in[0];
    const float* eb = (const float*)d_in[1];
    const float* ep = (const float*)d_in[2];
    const float* logA = (const float*)d_in[3];
    const float* Wd = (const float*)d_in[4];
    const float* bd = (const float*)d_in[5];
    const float* WB = (const float*)d_in[6];
    const float* bB = (const float*)d_in[7];
    const float* WC = (const float*)d_in[8];
    const float* bC = (const float*)d_in[9];
    const float* WDp = (const float*)d_in[10];
    const float* bDp = (const float*)d_in[11];
    const float* gamma = (const float*)d_in[12];
    const float* beta = (const float*)d_in[13];
    const float* Wh = (const float*)d_in[14];
    const float* bh = (const float*)d_in[15];
    float* out = (float*)d_out;

    size_t E = (size_t)MM * DD;                // 4,194,304 floats
    size_t EN = (size_t)MM * NN;               // 131,072
    size_t EC = (size_t)BB * DD * CC * NN;     // 2,097,152
    float* X = (float*)d_ws;
    float* HN = X + E;
    float* DEL = HN + E;
    float* D2 = DEL + E;
    float* BIc = D2 + E;
    float* CIc = BIc + EN;
    float* P = CIc + EN;
    float* LS = P + EC;
    bf16* HNb = (bf16*)(LS + EC);              // packed, E bf16 = 8 MB
    bf16* WtP = HNb + E;                       // packed weights: 278528*8 bf16

    embed_ln<<<MM / 4, 256, 0, stream>>>(ids, eb, ep, gamma, beta, X, HN, HNb);
    convert_weights<<<272, 256, 0, stream>>>(Wd, WDp, Wh, WtP);
    for (int l = 0; l < LL; l++) {
        const float* lA = logA + (size_t)l * DD * NN;
        gemm_pack<1, 16><<<2048, 256, 0, stream>>>(
            HNb, WtP + (size_t)l * 524288, bd + l * DD, bDp + l * DD, X, DEL, D2, 1024);
        scan1bc<<<BB * CC, 512, 0, stream>>>(DEL, HN, WB + (size_t)l * DD * NN, bB + l * NN,
                                             WC + (size_t)l * DD * NN, bC + l * NN, lA,
                                             P, LS, BIc, CIc);
        scan2<<<(BB * DD * NN) / 256, 256, 0, stream>>>(P, LS);
        if (l < LL - 1) {
            scan3ln<0><<<BB * CC, 512, 0, stream>>>(DEL, HN, BIc, CIc, lA, LS, D2,
                                                    gamma + (l + 1) * DD, beta + (l + 1) * DD,
                                                    X, HNb);
        } else {
            scan3ln<1><<<BB * CC, 512, 0, stream>>>(DEL, HN, BIc, CIc, lA, LS, D2,
                                                    nullptr, nullptr, X, HNb);
        }
    }
    // head: reads packed bf16(X_final) written by last scan3ln
    gemm_pack<0, 4><<<512, 256, 0, stream>>>(
        HNb, WtP + (size_t)2097152, bh, nullptr, nullptr, out, nullptr, VV);
}